// Round 5
// baseline (995.204 us; speedup 1.0000x reference)
//
#include <hip/hip_runtime.h>

namespace {

constexpr int kT = 51;      // input timesteps
constexpr int kOut = 20;    // decoder steps
constexpr float kL2E  = 1.4426950408889634f;   // log2(e)
constexpr float kL2E2 = 2.8853900817779268f;   // 2*log2(e)

typedef __attribute__((ext_vector_type(8))) short bf16x8;
typedef __attribute__((ext_vector_type(4))) float f32x4;
typedef __attribute__((ext_vector_type(2))) float f32x2;

union FragU {
    bf16x8 v;
    unsigned long long u64[2];
    unsigned int u32[4];
    unsigned short s[8];
};

__device__ __forceinline__ unsigned short f2bf(float x) {
    union { float f; unsigned int u; } v;
    v.f = x;
    unsigned int r = (v.u + 0x7fffu + ((v.u >> 16) & 1u)) >> 16;
    return (unsigned short)r;
}

// pack two floats to bf16x2 (low=bf(a), high=bf(b)): 2x v_add_u32 + v_perm_b32
__device__ __forceinline__ unsigned int packbf(float a, float b) {
    union { float f; unsigned int u; } ua, ub;
    ua.f = a; ub.f = b;
    return __builtin_amdgcn_perm(ub.u + 0x8000u, ua.u + 0x8000u, 0x07060302u);
}

// 8-float row -> bf16x8 A/B fragment (scaled)
__device__ __forceinline__ bf16x8 ldfrag(const float* __restrict__ p, float sc) {
    FragU fu;
#pragma unroll
    for (int j = 0; j < 8; ++j) fu.s[j] = f2bf(p[j] * sc);
    return fu.v;
}

// aug fragment: [Wih(4) | bias | 0 0 0], meaningful on q0 lanes only
__device__ __forceinline__ bf16x8 ldaug(const float* __restrict__ Wih,
                                        const float* __restrict__ bih,
                                        const float* __restrict__ bhh,
                                        int j, float sc, bool q0v, bool addbhh) {
    FragU fu;
    fu.u64[0] = 0; fu.u64[1] = 0;
    if (q0v) {
#pragma unroll
        for (int d = 0; d < 4; ++d) fu.s[d] = f2bf(Wih[j * 4 + d] * sc);
        float bias = addbhh ? (bih[j] + bhh[j]) : bih[j];
        fu.s[4] = f2bf(bias * sc);
    }
    return fu.v;
}

#define MFMA16(A, B, C) __builtin_amdgcn_mfma_f32_16x16x32_bf16((A), (B), (C), 0, 0, 0)

// ---- per-tile named registers (NO arrays -> SROA-proof, stays in VGPRs) ----
#define DECLT(T) \
    bf16x8 Wr##T##a, Wr##T##b, Wz##T##a, Wz##T##b, Wn##T##a, Wn##T##b; \
    bf16x8 Ur##T, Uz##T, Un##T; \
    f32x4 BN##T; \
    f32x4 H##T;

#define LOADT(T, RU, CU, Whh, Wih, bih, bhh) \
    Wr##T##a = ldfrag((Whh) + (RU) * 64 + qo,              kL2E);  \
    Wr##T##b = ldfrag((Whh) + (RU) * 64 + 32 + qo,         kL2E);  \
    Wz##T##a = ldfrag((Whh) + (64 + (RU)) * 64 + qo,       kL2E);  \
    Wz##T##b = ldfrag((Whh) + (64 + (RU)) * 64 + 32 + qo,  kL2E);  \
    Wn##T##a = ldfrag((Whh) + (128 + (RU)) * 64 + qo,      kL2E2); \
    Wn##T##b = ldfrag((Whh) + (128 + (RU)) * 64 + 32 + qo, kL2E2); \
    Ur##T = ldaug((Wih), (bih), (bhh), (RU),       kL2E,  q0v, true);  \
    Uz##T = ldaug((Wih), (bih), (bhh), 64 + (RU),  kL2E,  q0v, true);  \
    Un##T = ldaug((Wih), (bih), (bhh), 128 + (RU), kL2E2, q0v, false); \
    BN##T[0] = (bhh)[128 + (CU)] * kL2E2; \
    BN##T[1] = (bhh)[128 + (CU) + 1] * kL2E2; \
    BN##T[2] = (bhh)[128 + (CU) + 2] * kL2E2; \
    BN##T[3] = (bhh)[128 + (CU) + 3] * kL2E2;

// activation for the element pair (2U, 2U+1); shared-rcp sigmoid/tanh
#define ACTP(R, Z, Ni, Nh, H, U, NFOUT) { \
    f32x2 aa = { __builtin_amdgcn_exp2f(-(R)[2*(U)]), __builtin_amdgcn_exp2f(-(R)[2*(U)+1]) }; \
    f32x2 cc = { __builtin_amdgcn_exp2f(-(Z)[2*(U)]), __builtin_amdgcn_exp2f(-(Z)[2*(U)+1]) }; \
    f32x2 Aa = aa + onev, Cc = cc + onev; \
    f32x2 Pp = Aa * Cc; \
    float rpp = __builtin_amdgcn_rcpf(Pp.x * Pp.y); \
    f32x2 Ps = {Pp.y, Pp.x}; \
    f32x2 rp = rpp * Ps; \
    f32x2 rr = rp * Cc; \
    f32x2 zz = rp * Aa; \
    f32x2 Nh2 = {(Nh)[2*(U)], (Nh)[2*(U)+1]}; \
    f32x2 Ni2 = {(Ni)[2*(U)], (Ni)[2*(U)+1]}; \
    f32x2 p2 = __builtin_elementwise_fma(rr, Nh2, Ni2); \
    f32x2 Ee = { __builtin_amdgcn_exp2f(p2.x), __builtin_amdgcn_exp2f(p2.y) }; \
    f32x2 Dd = Ee + onev; \
    float rdd = __builtin_amdgcn_rcpf(Dd.x * Dd.y); \
    f32x2 Ds = {Dd.y, Dd.x}; \
    f32x2 tt = rdd * Ds; \
    f32x2 nn = __builtin_elementwise_fma(tt, m2v, onev); \
    f32x2 hh = {(H)[2*(U)], (H)[2*(U)+1]}; \
    f32x2 hv = __builtin_elementwise_fma(zz, hh - nn, nn); \
    (H)[2*(U)] = hv.x; (H)[2*(U)+1] = hv.y; \
    NFOUT = packbf(hv.x, hv.y); }

#define STEPT(T, NF0, NF1) { \
    f32x4 R = MFMA16(Ur##T, ba, z4); \
    R = MFMA16(Wr##T##a, bh0, R); \
    R = MFMA16(Wr##T##b, bh1, R); \
    f32x4 Z = MFMA16(Uz##T, ba, z4); \
    Z = MFMA16(Wz##T##a, bh0, Z); \
    Z = MFMA16(Wz##T##b, bh1, Z); \
    f32x4 Ni = MFMA16(Un##T, ba, z4); \
    f32x4 Nh = MFMA16(Wn##T##a, bh0, BN##T); \
    Nh = MFMA16(Wn##T##b, bh1, Nh); \
    ACTP(R, Z, Ni, Nh, H##T, 0, NF0); \
    ACTP(R, Z, Ni, Nh, H##T, 1, NF1); }

#define GRU_STEP() { \
    unsigned int nf0, nf1, nf2, nf3, nf4, nf5, nf6, nf7; \
    STEPT(0, nf0, nf1); \
    STEPT(1, nf2, nf3); \
    STEPT(2, nf4, nf5); \
    STEPT(3, nf6, nf7); \
    FragU f0, f1; \
    f0.u32[0] = nf0; f0.u32[1] = nf1; f0.u32[2] = nf2; f0.u32[3] = nf3; \
    f1.u32[0] = nf4; f1.u32[1] = nf5; f1.u32[2] = nf6; f1.u32[3] = nf7; \
    bh0 = f0.v; bh1 = f1.v; }

#define MAKE_BA() { \
    FragU fu; \
    fu.u32[0] = packbf(px0, px1); \
    fu.u32[1] = packbf(px2, px3); \
    fu.u32[2] = 0x3f80u; \
    fu.u32[3] = 0u; \
    ba = fu.v; }

// Fully wave-local GRU enc-dec: each wave owns ALL 64 hidden units for 16
// batch rows. No LDS, no barriers — the h feedback stays in registers.
//
// Scattered tile trick: A-tile t covers units S_t[4q+r] = 32*(t>>1)+8q+4*(t&1)+r.
// Lane (q,i)'s 16 C-outputs (4 tiles x 4 regs) are exactly the units
// {8q+j, 32+8q+j : j=0..7} — the positions of ITS OWN next-step B-frags.
// B-frag rebuild = 8 packbf, zero cross-lane ops.
//
// __launch_bounds__(256, 1): the (256,2) variant capped arch-VGPRs at 128
// (unified VGPR/AGPR budget split), forcing per-step scratch spills of the
// ~230-reg working set (rocprof: 533 MB scratch writes). min-waves=1 unlocks
// the full file; actual usage ~230 still gives 2 waves/SIMD at runtime.
__global__ __launch_bounds__(256, 1) void gru_encdec(
    const float* __restrict__ input,
    const float* __restrict__ eWih, const float* __restrict__ eWhh,
    const float* __restrict__ ebih, const float* __restrict__ ebhh,
    const float* __restrict__ dWih, const float* __restrict__ dWhh,
    const float* __restrict__ dbih, const float* __restrict__ dbhh,
    const float* __restrict__ linW, const float* __restrict__ linb,
    float* __restrict__ out)
{
    const int lane = (int)(threadIdx.x & 63u);
    const int w = (int)(threadIdx.x >> 6u);   // 4 independent waves per block
    const int q = lane >> 4;
    const int i = lane & 15;
    const bool q0v = (q == 0);
    const int qo = q * 8;
    const long bb = ((long)blockIdx.x * 4 + w) * 16 + i;   // this lane's batch row
    const float* __restrict__ xrow = input + bb * (kT * 4);
    // A-row gather base: row m=i of tile t -> unit 32*(t>>1)+4*(t&1)+ibase
    const int ibase = 8 * (i >> 2) + (i & 3);
    const int rowu0 = ibase,      rowu1 = 4 + ibase;
    const int rowu2 = 32 + ibase, rowu3 = 36 + ibase;
    const int cu0 = qo,      cu1 = 4 + qo;
    const int cu2 = 32 + qo, cu3 = 36 + qo;

    const f32x4 z4 = {0.f, 0.f, 0.f, 0.f};
    const f32x2 onev = {1.f, 1.f};
    const f32x2 m2v = {-2.f, -2.f};
    const bf16x8 zfr = {0, 0, 0, 0, 0, 0, 0, 0};

    DECLT(0) DECLT(1) DECLT(2) DECLT(3)
    bf16x8 bh0, bh1, ba;
    float px0, px1, px2, px3;

    // ---------------- encoder ----------------
    H0 = z4; H1 = z4; H2 = z4; H3 = z4;
    bh0 = zfr; bh1 = zfr;
    LOADT(0, rowu0, cu0, eWhh, eWih, ebih, ebhh)
    LOADT(1, rowu1, cu1, eWhh, eWih, ebih, ebhh)
    LOADT(2, rowu2, cu2, eWhh, eWih, ebih, ebhh)
    LOADT(3, rowu3, cu3, eWhh, eWih, ebih, ebhh)

    float4 xp = *(const float4*)(xrow);
    float4 xn = *(const float4*)(xrow + 4);
#pragma unroll 1
    for (int s = 0; s < kT - 1; ++s) {
        px0 = xn.x - xp.x; px1 = xn.y - xp.y;
        px2 = xn.z - xp.z; px3 = xn.w - xp.w;
        xp = xn;
        int idx = s + 2; if (idx > kT - 1) idx = kT - 1;
        xn = *(const float4*)(xrow + idx * 4);   // prefetch next x
        MAKE_BA();
        GRU_STEP();
    }
    const float4 off = xp;   // input[b][T-1]; px = diffs[b][T-2]

    // ---------------- decoder ----------------
    LOADT(0, rowu0, cu0, dWhh, dWih, dbih, dbhh)
    LOADT(1, rowu1, cu1, dWhh, dWih, dbih, dbhh)
    LOADT(2, rowu2, cu2, dWhh, dWih, dbih, dbhh)
    LOADT(3, rowu3, cu3, dWhh, dWih, dbih, dbhh)

    // linear head: A[m=i][k=8q+j] = linW[i][k] for i<4; bias via scalar adds
    bf16x8 AL0 = zfr, AL1 = zfr;
    if (i < 4) {
        AL0 = ldfrag(linW + i * 64 + qo, 1.0f);
        AL1 = ldfrag(linW + i * 64 + 32 + qo, 1.0f);
    }
    const float lb0 = linb[0], lb1 = linb[1], lb2 = linb[2], lb3 = linb[3];

    float* __restrict__ orow = out + bb * (kOut * 4);
#pragma unroll 1
    for (int s = 0; s < kOut; ++s) {
        MAKE_BA();
        GRU_STEP();   // bh frags now hold NEW h
        f32x4 X = MFMA16(AL0, bh0, z4);
        X = MFMA16(AL1, bh1, X);
        // q0 lanes: X[r] = x_d, d=r, col=i=batch; q>0 lanes get X=0 and their
        // px drift (+lb) is harmless — those B rows hit zero A columns.
        px0 += X[0] + lb0; px1 += X[1] + lb1;
        px2 += X[2] + lb2; px3 += X[3] + lb3;
        if (q0v) {
            float4 v;
            v.x = px0 + off.x; v.y = px1 + off.y;
            v.z = px2 + off.z; v.w = px3 + off.w;
            *(float4*)(orow + s * 4) = v;
        }
    }
}

}  // namespace

extern "C" void kernel_launch(void* const* d_in, const int* in_sizes, int n_in,
                              void* d_out, int out_size, void* d_ws, size_t ws_size,
                              hipStream_t stream) {
    const float* input = (const float*)d_in[0];
    const float* eWih = (const float*)d_in[1];
    const float* eWhh = (const float*)d_in[2];
    const float* ebih = (const float*)d_in[3];
    const float* ebhh = (const float*)d_in[4];
    const float* dWih = (const float*)d_in[5];
    const float* dWhh = (const float*)d_in[6];
    const float* dbih = (const float*)d_in[7];
    const float* dbhh = (const float*)d_in[8];
    const float* linW = (const float*)d_in[9];
    const float* linb = (const float*)d_in[10];
    float* out = (float*)d_out;

    const int B = in_sizes[0] / (kT * 4);
    const int nblocks = B / 64;   // 4 independent waves x 16 rows per block
    gru_encdec<<<nblocks, 256, 0, stream>>>(input, eWih, eWhh, ebih, ebhh,
                                            dWih, dWhh, dbih, dbhh,
                                            linW, linb, out);
}

// Round 6
// 648.632 us; speedup vs baseline: 1.5343x; 1.5343x over previous
//
#include <hip/hip_runtime.h>

namespace {

constexpr int kT = 51;      // input timesteps
constexpr int kOut = 20;    // decoder steps
constexpr float kL2E  = 1.4426950408889634f;   // log2(e)
constexpr float kL2E2 = 2.8853900817779268f;   // 2*log2(e)

typedef __attribute__((ext_vector_type(8))) short bf16x8;
typedef __attribute__((ext_vector_type(4))) float f32x4;
typedef __attribute__((ext_vector_type(2))) float f32x2;

union FragU {
    bf16x8 v;
    unsigned long long u64[2];
    unsigned int u32[4];
    unsigned short s[8];
};

__device__ __forceinline__ unsigned short f2bf(float x) {
    union { float f; unsigned int u; } v;
    v.f = x;
    unsigned int r = (v.u + 0x7fffu + ((v.u >> 16) & 1u)) >> 16;
    return (unsigned short)r;
}

// single-instruction pack: low = bf16(a), high = bf16(b) (RNE).
// Pure-arithmetic inline asm (no memory semantics) — replaces the 3-op
// perm-based pack; ~40 VALU insts saved per GRU step.
__device__ __forceinline__ unsigned int cvtpk(float a, float b) {
    unsigned int r;
    asm("v_cvt_pk_bf16_f32 %0, %1, %2" : "=v"(r) : "v"(a), "v"(b));
    return r;
}

// GRU enc-dec, 4-way unit split x 4 batch groups. Block = 256 thr = 4 waves,
// handling 64 batch rows (groups g=0..3 of 16). Wave w owns hidden units
// [16w,16w+16) for ALL groups (weight frags shared). h' slices exchanged via
// double-buffered LDS, one __syncthreads per step.
// MFMA 16x16x32 layouts: A lane(q,i)=A[m=i][k=8q+j]; B lane(q,i)=B[k=8q+j][n=i];
// C lane(q,i)=C[row=4q+r][col=i]. Weights pre-scaled by log2e (r,z) / 2log2e
// (n) so activations use raw v_exp_f32. Activations run as f32x2 over the
// (even,odd) group pair -> v_pk_*_f32; rcp product-sharing pairs the two
// groups' units: 4 trans/unit (3 exp2 + 1 rcp).
__global__ __launch_bounds__(256, 2) void gru_encdec(
    const float* __restrict__ input,
    const float* __restrict__ eWih, const float* __restrict__ eWhh,
    const float* __restrict__ ebih, const float* __restrict__ ebhh,
    const float* __restrict__ dWih, const float* __restrict__ dWhh,
    const float* __restrict__ dbih, const float* __restrict__ dbhh,
    const float* __restrict__ linW, const float* __restrict__ linb,
    float* __restrict__ out)
{
    // h exchange: [dbuf][group][16 rows x 64 units, stride 68 bf16]
    __shared__ __align__(16) unsigned short hbuf[2][4][16 * 68];

    const int lane = (int)(threadIdx.x & 63u);
    const int w = (int)(threadIdx.x >> 6u);   // unit-quarter owner
    const int q = lane >> 4;
    const int i = lane & 15;
    const bool q0 = (q == 0);
    const long bb = (long)blockIdx.x * 64 + i;   // batch row for group 0

    const float* xrow[4];
#pragma unroll
    for (int g = 0; g < 4; ++g) xrow[g] = input + (bb + 16 * g) * (kT * 4);

    // Per-wave weight fragments: l = 0 (r), 1 (z), 2 (n); tau = 4*l + w
    bf16x8 WA[3][2];     // Whh frags, [l][K-half]
    bf16x8 WAUG[3];      // [Wih(4) | bias | 0...] frags (q0 lanes meaningful)
    f32x4 bhhn4;         // bhh_n * 2l2e as C-init
    float hp[4][4];      // fp32 h per group, [g][r] = h[b][u=16w+4q+r]
    bf16x8 bh[4][2];     // h B-frags per group / K-half
    float px[4][4];
    const f32x4 z4 = {0.f, 0.f, 0.f, 0.f};
    const bf16x8 zfr = {0, 0, 0, 0, 0, 0, 0, 0};

    auto load_whh = [&](const float* __restrict__ Whh) {
#pragma unroll
        for (int l = 0; l < 3; ++l) {
            const int tau = 4 * l + w;
            const float sc = (l < 2) ? kL2E : kL2E2;
#pragma unroll
            for (int f = 0; f < 2; ++f) {
                const float* ptr = Whh + (tau * 16 + i) * 64 + f * 32 + q * 8;
                FragU fu;
#pragma unroll
                for (int j = 0; j < 8; ++j) fu.s[j] = f2bf(ptr[j] * sc);
                WA[l][f] = fu.v;
            }
        }
    };

    auto load_aug = [&](const float* __restrict__ Wih,
                        const float* __restrict__ bih,
                        const float* __restrict__ bhh) {
#pragma unroll
        for (int l = 0; l < 3; ++l) {
            const int tau = 4 * l + w;
            const float sc = (l < 2) ? kL2E : kL2E2;
            FragU fu;
            fu.u64[0] = 0; fu.u64[1] = 0;
            if (q0) {
                int j = tau * 16 + i;
#pragma unroll
                for (int d = 0; d < 4; ++d) fu.s[d] = f2bf(Wih[j * 4 + d] * sc);
                float bias = (l < 2) ? (bih[j] + bhh[j]) : bih[j];
                fu.s[4] = f2bf(bias * sc);
            }
            WAUG[l] = fu.v;
        }
#pragma unroll
        for (int r = 0; r < 4; ++r)
            bhhn4[r] = bhh[128 + 16 * w + 4 * q + r] * kL2E2;
    };

    // B-frag from px: only k<5 rows hit nonzero A columns, so no lane masking
    // needed (q>0 lanes / s[5..7] hit zero A columns).
    auto make_baug = [&](const float* pxv) -> bf16x8 {
        FragU fu;
        fu.u32[0] = cvtpk(pxv[0], pxv[1]);
        fu.u32[1] = cvtpk(pxv[2], pxv[3]);
        fu.u32[2] = 0x3f80u;  // bf16(1.0) -> bias column
        fu.u32[3] = 0u;
        return fu.v;
    };

    // One GRU step for all 4 groups; ssel = LDS dbuf (0/1). Groups processed
    // as 2 pairs to bound accumulator liveness; activations in f32x2 pairs.
    auto gru_step = [&](int ssel, const bf16x8* ba) {
#pragma unroll
        for (int p = 0; p < 2; ++p) {
            const int g0 = 2 * p, g1 = 2 * p + 1;
            f32x4 R[2], Z[2], Ni[2], Nh[2];
#pragma unroll
            for (int k = 0; k < 2; ++k) {
                const int g = 2 * p + k;
                R[k] = __builtin_amdgcn_mfma_f32_16x16x32_bf16(WAUG[0], ba[g], z4, 0, 0, 0);
                R[k] = __builtin_amdgcn_mfma_f32_16x16x32_bf16(WA[0][0], bh[g][0], R[k], 0, 0, 0);
                R[k] = __builtin_amdgcn_mfma_f32_16x16x32_bf16(WA[0][1], bh[g][1], R[k], 0, 0, 0);
                Z[k] = __builtin_amdgcn_mfma_f32_16x16x32_bf16(WAUG[1], ba[g], z4, 0, 0, 0);
                Z[k] = __builtin_amdgcn_mfma_f32_16x16x32_bf16(WA[1][0], bh[g][0], Z[k], 0, 0, 0);
                Z[k] = __builtin_amdgcn_mfma_f32_16x16x32_bf16(WA[1][1], bh[g][1], Z[k], 0, 0, 0);
                Ni[k] = __builtin_amdgcn_mfma_f32_16x16x32_bf16(WAUG[2], ba[g], z4, 0, 0, 0);
                Nh[k] = __builtin_amdgcn_mfma_f32_16x16x32_bf16(WA[2][0], bh[g][0], bhhn4, 0, 0, 0);
                Nh[k] = __builtin_amdgcn_mfma_f32_16x16x32_bf16(WA[2][1], bh[g][1], Nh[k], 0, 0, 0);
            }
            float hva[4], hvb[4];
            const f32x2 one = {1.f, 1.f};
            const f32x2 m2 = {-2.f, -2.f};
#pragma unroll
            for (int r = 0; r < 4; ++r) {
                f32x2 a = { __builtin_amdgcn_exp2f(-R[0][r]),
                            __builtin_amdgcn_exp2f(-R[1][r]) };
                f32x2 c = { __builtin_amdgcn_exp2f(-Z[0][r]),
                            __builtin_amdgcn_exp2f(-Z[1][r]) };
                f32x2 A = a + one, C = c + one;
                f32x2 P = A * C;
                float rpp = __builtin_amdgcn_rcpf(P.x * P.y);
                f32x2 Ps = {P.y, P.x};
                f32x2 rp = rpp * Ps;              // {1/P.x, 1/P.y}
                f32x2 rr = rp * C;                // sigmoid(xr) pair
                f32x2 zz = rp * A;                // sigmoid(xz) pair
                f32x2 Nh2 = {Nh[0][r], Nh[1][r]};
                f32x2 Ni2 = {Ni[0][r], Ni[1][r]};
                f32x2 p2 = __builtin_elementwise_fma(rr, Nh2, Ni2);
                f32x2 E = { __builtin_amdgcn_exp2f(p2.x),
                            __builtin_amdgcn_exp2f(p2.y) };
                f32x2 D = E + one;
                float rdd = __builtin_amdgcn_rcpf(D.x * D.y);
                f32x2 Ds = {D.y, D.x};
                f32x2 t = rdd * Ds;
                f32x2 n = __builtin_elementwise_fma(t, m2, one);   // tanh
                f32x2 h = {hp[g0][r], hp[g1][r]};
                f32x2 hv = __builtin_elementwise_fma(zz, h - n, n);
                hp[g0][r] = hv.x; hp[g1][r] = hv.y;
                hva[r] = hv.x;    hvb[r] = hv.y;
            }
            uint2 wva, wvb;
            wva.x = cvtpk(hva[0], hva[1]); wva.y = cvtpk(hva[2], hva[3]);
            wvb.x = cvtpk(hvb[0], hvb[1]); wvb.y = cvtpk(hvb[2], hvb[3]);
            *(uint2*)&hbuf[ssel][g0][i * 68 + 16 * w + 4 * q] = wva;
            *(uint2*)&hbuf[ssel][g1][i * 68 + 16 * w + 4 * q] = wvb;
        }
        __syncthreads();  // h' slices visible block-wide
#pragma unroll
        for (int g = 0; g < 4; ++g) {
            const unsigned short* hw = hbuf[ssel][g];
            FragU fA, fB;
            fA.u64[0] = *(const unsigned long long*)&hw[i * 68 + 8 * q];
            fA.u64[1] = *(const unsigned long long*)&hw[i * 68 + 8 * q + 4];
            fB.u64[0] = *(const unsigned long long*)&hw[i * 68 + 32 + 8 * q];
            fB.u64[1] = *(const unsigned long long*)&hw[i * 68 + 32 + 8 * q + 4];
            bh[g][0] = fA.v;
            bh[g][1] = fB.v;
        }
    };

    // ---------------- encoder ----------------
#pragma unroll
    for (int g = 0; g < 4; ++g) {
#pragma unroll
        for (int r = 0; r < 4; ++r) hp[g][r] = 0.f;
        bh[g][0] = zfr;
        bh[g][1] = zfr;
    }
    load_whh(eWhh);
    load_aug(eWih, ebih, ebhh);

    float4 xp[4], xn[4];
#pragma unroll
    for (int g = 0; g < 4; ++g) {
        xp[g] = *(const float4*)(xrow[g]);
        xn[g] = *(const float4*)(xrow[g] + 4);
    }
    bf16x8 ba[4];
#pragma unroll 2
    for (int s = 0; s < kT - 1; ++s) {
#pragma unroll
        for (int g = 0; g < 4; ++g) {
            px[g][0] = xn[g].x - xp[g].x; px[g][1] = xn[g].y - xp[g].y;
            px[g][2] = xn[g].z - xp[g].z; px[g][3] = xn[g].w - xp[g].w;
            xp[g] = xn[g];
        }
        int idx = s + 2; if (idx > kT - 1) idx = kT - 1;
#pragma unroll
        for (int g = 0; g < 4; ++g)
            xn[g] = *(const float4*)(xrow[g] + idx * 4);   // prefetch next x
#pragma unroll
        for (int g = 0; g < 4; ++g) ba[g] = make_baug(px[g]);
        gru_step(s & 1, ba);
    }
    // after loop: xp[g] = input[b][T-1] (offset); px[g] = diffs[b][T-2]
    float4 off[4];
#pragma unroll
    for (int g = 0; g < 4; ++g) off[g] = xp[g];

    // ---------------- decoder ----------------
    load_whh(dWhh);
    load_aug(dWih, dbih, dbhh);

    // linear head frags (all waves hold them; head computed redundantly so the
    // fp32 px chains stay wave-local and bitwise-identical across waves).
    // Bias applied as uniform scalar adds (verified in rounds 4/5) — saves the
    // AL2 aug-MFMA per group per step.
    bf16x8 AL0, AL1;
    {
        FragU a0, a1;
        a0.u64[0] = a0.u64[1] = 0;
        a1.u64[0] = a1.u64[1] = 0;
        if (i < 4) {
            const float* p0 = linW + i * 64 + q * 8;
            const float* p1 = linW + i * 64 + 32 + q * 8;
#pragma unroll
            for (int j = 0; j < 8; ++j) {
                a0.s[j] = f2bf(p0[j]);
                a1.s[j] = f2bf(p1[j]);
            }
        }
        AL0 = a0.v; AL1 = a1.v;
    }
    const float lb0 = linb[0], lb1 = linb[1], lb2 = linb[2], lb3 = linb[3];

#pragma unroll 2
    for (int s = 0; s < kOut; ++s) {
#pragma unroll
        for (int g = 0; g < 4; ++g) ba[g] = make_baug(px[g]);
        gru_step(s & 1, ba);  // bh frags now hold NEW h
#pragma unroll
        for (int g = 0; g < 4; ++g) {
            f32x4 X = __builtin_amdgcn_mfma_f32_16x16x32_bf16(AL0, bh[g][0], z4, 0, 0, 0);
            X = __builtin_amdgcn_mfma_f32_16x16x32_bf16(AL1, bh[g][1], X, 0, 0, 0);
            // q0 lanes: X[r] = x_d, d=r, col=i=batch. fp32 px chains.
            // q>0 lanes: X=0, px drifts by +lb — harmless (their ba rows hit
            // zero A columns; verified rounds 4/5).
            px[g][0] += X[0] + lb0; px[g][1] += X[1] + lb1;
            px[g][2] += X[2] + lb2; px[g][3] += X[3] + lb3;
        }
        // direct global store: wave g's q0 lanes own group g's 16 rows.
#pragma unroll
        for (int g = 0; g < 4; ++g) {
            if (w == g && q0) {
                float* op = out + (bb + 16 * g) * (kOut * 4) + s * 4;
                float4 v;
                v.x = px[g][0] + off[g].x; v.y = px[g][1] + off[g].y;
                v.z = px[g][2] + off[g].z; v.w = px[g][3] + off[g].w;
                *(float4*)op = v;
            }
        }
    }
}

}  // namespace

extern "C" void kernel_launch(void* const* d_in, const int* in_sizes, int n_in,
                              void* d_out, int out_size, void* d_ws, size_t ws_size,
                              hipStream_t stream) {
    const float* input = (const float*)d_in[0];
    const float* eWih = (const float*)d_in[1];
    const float* eWhh = (const float*)d_in[2];
    const float* ebih = (const float*)d_in[3];
    const float* ebhh = (const float*)d_in[4];
    const float* dWih = (const float*)d_in[5];
    const float* dWhh = (const float*)d_in[6];
    const float* dbih = (const float*)d_in[7];
    const float* dbhh = (const float*)d_in[8];
    const float* linW = (const float*)d_in[9];
    const float* linb = (const float*)d_in[10];
    float* out = (float*)d_out;

    const int B = in_sizes[0] / (kT * 4);
    const int nblocks = B / 64;   // 64 batch rows per block (4 groups of 16)
    gru_encdec<<<nblocks, 256, 0, stream>>>(input, eWih, eWhh, ebih, ebhh,
                                            dWih, dWhh, dbih, dbhh,
                                            linW, linb, out);
}